// Round 1
// baseline (1841.923 us; speedup 1.0000x reference)
//
#include <hip/hip_runtime.h>

constexpr float BN_EPS = 1e-5f;

// ---------------- init: deg=1 (self loop), zero BN stat accumulators ----------------
__global__ void k_init(int* __restrict__ deg, float* __restrict__ stats, int n) {
    int i = blockIdx.x * blockDim.x + threadIdx.x;
    if (i < n) deg[i] = 1;
    if (blockIdx.x == 0 && threadIdx.x < 256) stats[threadIdx.x] = 0.f;
}

// ---------------- count in-degree over edges ----------------
__global__ void k_count(const int* __restrict__ dst, int* __restrict__ deg, int E) {
    int i = blockIdx.x * blockDim.x + threadIdx.x;
    int stride = gridDim.x * blockDim.x;
    for (int e = i; e < E; e += stride) atomicAdd(&deg[dst[e]], 1);
}

__global__ void k_dinv(const int* __restrict__ deg, float* __restrict__ dinv, int n) {
    int i = blockIdx.x * blockDim.x + threadIdx.x;
    if (i < n) dinv[i] = rsqrtf((float)deg[i]);
}

// ---------------- GEMM1: g1 = dinv ⊙ (x @ W1^T), dual-store into agg1 (self loop) ----
// x [n][128], W1 [128][128] row-major (W1[j][k]), out cols j = 0..127
__global__ __launch_bounds__(256) void k_gemm1(const float* __restrict__ x,
                                               const float* __restrict__ W1,
                                               const float* __restrict__ dinv,
                                               float* __restrict__ g1,
                                               float* __restrict__ agg1, int n) {
    __shared__ float As[16][68];   // As[k][row], 272B row stride (16B aligned, 2-way max)
    __shared__ float Bs[16][132];  // Bs[k][col], 528B row stride
    const int tid = threadIdx.x;
    const int row0 = blockIdx.x * 64;
    const int tx = tid & 31, ty = tid >> 5;   // cols tx*4.., rows ty*8..
    float acc[8][4] = {};
    for (int k0 = 0; k0 < 128; k0 += 16) {
        { // stage A: 64 rows x 16 k
            int r = tid >> 2;
            int kk4 = (tid & 3) * 4;
            int grow = row0 + r;
            float4 v = make_float4(0.f, 0.f, 0.f, 0.f);
            if (grow < n) v = *(const float4*)&x[(size_t)grow * 128 + k0 + kk4];
            As[kk4 + 0][r] = v.x; As[kk4 + 1][r] = v.y;
            As[kk4 + 2][r] = v.z; As[kk4 + 3][r] = v.w;
        }
        { // stage B: 128 cols x 16 k (transpose of W1 rows)
            int j = tid >> 1;
            int kb = (tid & 1) * 8;
            const float* wp = &W1[(size_t)j * 128 + k0 + kb];
            float4 v0 = *(const float4*)wp;
            float4 v1 = *(const float4*)(wp + 4);
            Bs[kb + 0][j] = v0.x; Bs[kb + 1][j] = v0.y; Bs[kb + 2][j] = v0.z; Bs[kb + 3][j] = v0.w;
            Bs[kb + 4][j] = v1.x; Bs[kb + 5][j] = v1.y; Bs[kb + 6][j] = v1.z; Bs[kb + 7][j] = v1.w;
        }
        __syncthreads();
#pragma unroll
        for (int kk = 0; kk < 16; ++kk) {
            float4 a0 = *(const float4*)&As[kk][ty * 8];
            float4 a1 = *(const float4*)&As[kk][ty * 8 + 4];
            float4 b  = *(const float4*)&Bs[kk][tx * 4];
            float a[8] = {a0.x, a0.y, a0.z, a0.w, a1.x, a1.y, a1.z, a1.w};
            float bb[4] = {b.x, b.y, b.z, b.w};
#pragma unroll
            for (int r = 0; r < 8; ++r)
#pragma unroll
                for (int c = 0; c < 4; ++c) acc[r][c] = fmaf(a[r], bb[c], acc[r][c]);
        }
        __syncthreads();
    }
#pragma unroll
    for (int r = 0; r < 8; ++r) {
        int grow = row0 + ty * 8 + r;
        if (grow < n) {
            float di = dinv[grow];
            float4 v = make_float4(acc[r][0] * di, acc[r][1] * di, acc[r][2] * di, acc[r][3] * di);
            size_t o = (size_t)grow * 128 + tx * 4;
            *(float4*)&g1[o] = v;
            *(float4*)&agg1[o] = v;
        }
    }
}

// ---------------- scatter: agg[dst] += g[src], one wave per edge ----------------
template <int F>
__global__ __launch_bounds__(256) void k_scatter(const int* __restrict__ src,
                                                 const int* __restrict__ dst,
                                                 const float* __restrict__ g,
                                                 float* __restrict__ agg, int E) {
    int gtid = blockIdx.x * blockDim.x + threadIdx.x;
    int wave = gtid >> 6;
    int lane = threadIdx.x & 63;
    int nwaves = (gridDim.x * blockDim.x) >> 6;
    for (int e = wave; e < E; e += nwaves) {
        int s = src[e];
        int d = dst[e];
        const float* gs = g + (size_t)s * F;
        float* ad = agg + (size_t)d * F;
        if (F == 128) {
            float2 v = *(const float2*)&gs[lane * 2];
            unsafeAtomicAdd(&ad[lane * 2 + 0], v.x);
            unsafeAtomicAdd(&ad[lane * 2 + 1], v.y);
        } else {
            unsafeAtomicAdd(&ad[lane], gs[lane]);
        }
    }
}

// ---------------- finalize layer1: h = agg*dinv + b1 (in place), BN stats ----------------
__global__ __launch_bounds__(256) void k_finalize1(float* __restrict__ h,
                                                   const float* __restrict__ dinv,
                                                   const float* __restrict__ b1,
                                                   float* __restrict__ stats, int n) {
    __shared__ float red[256];
    const int tid = threadIdx.x;
    const int f = tid & 127;
    const float bias = b1[f];
    float sum = 0.f, sq = 0.f;
    int rowsPer = (n + gridDim.x - 1) / gridDim.x;
    int r0 = blockIdx.x * rowsPer;
    int r1 = min(n, r0 + rowsPer);
    for (int r = r0 + (tid >> 7); r < r1; r += 2) {
        size_t o = (size_t)r * 128 + f;
        float v = fmaf(h[o], dinv[r], bias);
        h[o] = v;
        sum += v;
        sq = fmaf(v, v, sq);
    }
    red[tid] = sum;
    __syncthreads();
    if (tid < 128) sum = red[tid] + red[tid + 128];
    __syncthreads();
    red[tid] = sq;
    __syncthreads();
    if (tid < 128) {
        sq = red[tid] + red[tid + 128];
        atomicAdd(&stats[f], sum);
        atomicAdd(&stats[128 + f], sq);
    }
}

// ---------------- BN scale/shift from sums ----------------
__global__ void k_bnfinal(float* __restrict__ stats, const float* __restrict__ gamma,
                          const float* __restrict__ beta, int n) {
    int f = threadIdx.x;  // 128 threads
    float inv_n = 1.f / (float)n;
    float mean = stats[f] * inv_n;
    float var = stats[128 + f] * inv_n - mean * mean;
    float sc = gamma[f] * rsqrtf(var + BN_EPS);
    stats[256 + f] = sc;
    stats[384 + f] = fmaf(-mean, sc, beta[f]);
}

// ---------------- GEMM2: g2 = dinv ⊙ (relu(BN(h1)) @ W2^T), dual-store agg2 ----------------
// h1 [n][128] raw (pre-BN); W2 [64][128]
__global__ __launch_bounds__(256) void k_gemm2(const float* __restrict__ h1,
                                               const float* __restrict__ W2,
                                               const float* __restrict__ dinv,
                                               const float* __restrict__ stats,
                                               float* __restrict__ g2,
                                               float* __restrict__ agg2, int n) {
    __shared__ float As[16][68];
    __shared__ float Bs[16][68];
    __shared__ float sSc[128], sSh[128];
    const int tid = threadIdx.x;
    if (tid < 128) {
        sSc[tid] = stats[256 + tid];
        sSh[tid] = stats[384 + tid];
    }
    const int row0 = blockIdx.x * 64;
    const int tx = tid & 15, ty = tid >> 4;  // cols tx*4.., rows ty*4..
    float acc[4][4] = {};
    __syncthreads();
    for (int k0 = 0; k0 < 128; k0 += 16) {
        { // stage A with fused BN + ReLU
            int r = tid >> 2;
            int kk4 = (tid & 3) * 4;
            int grow = row0 + r;
            float4 v = make_float4(0.f, 0.f, 0.f, 0.f);
            if (grow < n) v = *(const float4*)&h1[(size_t)grow * 128 + k0 + kk4];
            int k = k0 + kk4;
            As[kk4 + 0][r] = fmaxf(fmaf(v.x, sSc[k + 0], sSh[k + 0]), 0.f);
            As[kk4 + 1][r] = fmaxf(fmaf(v.y, sSc[k + 1], sSh[k + 1]), 0.f);
            As[kk4 + 2][r] = fmaxf(fmaf(v.z, sSc[k + 2], sSh[k + 2]), 0.f);
            As[kk4 + 3][r] = fmaxf(fmaf(v.w, sSc[k + 3], sSh[k + 3]), 0.f);
        }
        { // stage B: 64 cols x 16 k
            int j = tid >> 2;
            int kb = (tid & 3) * 4;
            float4 v = *(const float4*)&W2[(size_t)j * 128 + k0 + kb];
            Bs[kb + 0][j] = v.x; Bs[kb + 1][j] = v.y;
            Bs[kb + 2][j] = v.z; Bs[kb + 3][j] = v.w;
        }
        __syncthreads();
#pragma unroll
        for (int kk = 0; kk < 16; ++kk) {
            float4 a = *(const float4*)&As[kk][ty * 4];
            float4 b = *(const float4*)&Bs[kk][tx * 4];
            float aa[4] = {a.x, a.y, a.z, a.w};
            float bb[4] = {b.x, b.y, b.z, b.w};
#pragma unroll
            for (int r = 0; r < 4; ++r)
#pragma unroll
                for (int c = 0; c < 4; ++c) acc[r][c] = fmaf(aa[r], bb[c], acc[r][c]);
        }
        __syncthreads();
    }
#pragma unroll
    for (int r = 0; r < 4; ++r) {
        int grow = row0 + ty * 4 + r;
        if (grow < n) {
            float di = dinv[grow];
            float4 v = make_float4(acc[r][0] * di, acc[r][1] * di, acc[r][2] * di, acc[r][3] * di);
            size_t o = (size_t)grow * 64 + tx * 4;
            *(float4*)&g2[o] = v;
            *(float4*)&agg2[o] = v;
        }
    }
}

// ---------------- finalize layer2: out = agg2*dinv + b2 ----------------
__global__ __launch_bounds__(256) void k_finalize2(const float* __restrict__ agg2,
                                                   const float* __restrict__ dinv,
                                                   const float* __restrict__ b2,
                                                   float* __restrict__ out, int n) {
    int i = blockIdx.x * blockDim.x + threadIdx.x;
    int total = n * 32;  // float2 granules
    int stride = gridDim.x * blockDim.x;
    for (; i < total; i += stride) {
        int row = i >> 5;
        int c2 = (i & 31) * 2;
        float di = dinv[row];
        float2 v = *(const float2*)&agg2[(size_t)row * 64 + c2];
        float2 o;
        o.x = fmaf(v.x, di, b2[c2 + 0]);
        o.y = fmaf(v.y, di, b2[c2 + 1]);
        *(float2*)&out[(size_t)row * 64 + c2] = o;
    }
}

extern "C" void kernel_launch(void* const* d_in, const int* in_sizes, int n_in,
                              void* d_out, int out_size, void* d_ws, size_t ws_size,
                              hipStream_t stream) {
    const float* x     = (const float*)d_in[0];
    const int*   ei    = (const int*)d_in[1];
    const float* W1    = (const float*)d_in[2];
    const float* b1    = (const float*)d_in[3];
    const float* gamma = (const float*)d_in[4];
    const float* beta  = (const float*)d_in[5];
    const float* W2    = (const float*)d_in[6];
    const float* b2    = (const float*)d_in[7];
    float* out = (float*)d_out;

    const int n = in_sizes[0] / 128;
    const int E = in_sizes[1] / 2;
    const int* src = ei;
    const int* dst = ei + E;

    char* ws = (char*)d_ws;
    const int Np = (n + 255) & ~255;
    int*   deg   = (int*)ws;
    float* dinv  = (float*)(ws + (size_t)Np * 4);
    float* stats = dinv + Np;                 // [0,128)=sum [128,256)=sumsq [256,384)=scale [384,512)=shift
    float* g1    = stats + 512;               // n*128
    float* agg1  = g1 + (size_t)n * 128;      // n*128
    float* g2    = g1;                        // reuse (g1 dead after scatter1)
    float* agg2  = g1 + (size_t)n * 64;       // second half of g1 buffer

    const int nb = (n + 255) / 256;
    const int gb = (n + 63) / 64;

    hipLaunchKernelGGL(k_init, dim3(nb), dim3(256), 0, stream, deg, stats, n);
    hipLaunchKernelGGL(k_count, dim3(1024), dim3(256), 0, stream, dst, deg, E);
    hipLaunchKernelGGL(k_dinv, dim3(nb), dim3(256), 0, stream, deg, dinv, n);

    hipLaunchKernelGGL(k_gemm1, dim3(gb), dim3(256), 0, stream, x, W1, dinv, g1, agg1, n);
    hipLaunchKernelGGL(k_scatter<128>, dim3(2048), dim3(256), 0, stream, src, dst, g1, agg1, E);
    hipLaunchKernelGGL(k_finalize1, dim3(nb), dim3(256), 0, stream, agg1, dinv, b1, stats, n);
    hipLaunchKernelGGL(k_bnfinal, dim3(1), dim3(128), 0, stream, stats, gamma, beta, n);

    hipLaunchKernelGGL(k_gemm2, dim3(gb), dim3(256), 0, stream, agg1, W2, dinv, stats, g2, agg2, n);
    hipLaunchKernelGGL(k_scatter<64>, dim3(2048), dim3(256), 0, stream, src, dst, g2, agg2, E);
    hipLaunchKernelGGL(k_finalize2, dim3(2048), dim3(256), 0, stream, agg2, dinv, b2, out, n);
}

// Round 2
// 826.654 us; speedup vs baseline: 2.2282x; 2.2282x over previous
//
#include <hip/hip_runtime.h>

constexpr float BN_EPS = 1e-5f;

// ---------------- init: zero deg counters + BN stat accumulators ----------------
__global__ void k_init(int* __restrict__ deg, float* __restrict__ stats, int n) {
    int i = blockIdx.x * blockDim.x + threadIdx.x;
    if (i < n) deg[i] = 0;
    if (blockIdx.x == 0 && threadIdx.x < 256) stats[threadIdx.x] = 0.f;
}

// ---------------- count in-degree over edges (excl self loops) ----------------
__global__ void k_count(const int* __restrict__ dst, int* __restrict__ deg, int E) {
    int i = blockIdx.x * blockDim.x + threadIdx.x;
    int stride = gridDim.x * blockDim.x;
    for (int e = i; e < E; e += stride) atomicAdd(&deg[dst[e]], 1);
}

// ---------------- hierarchical exclusive scan of deg -> rowptr (chunk = 1024) ----------------
__global__ __launch_bounds__(256) void k_blocksum(const int* __restrict__ deg, int* __restrict__ bsum, int n) {
    __shared__ int red[256];
    int b = blockIdx.x, tid = threadIdx.x;
    int i0 = b * 1024 + tid * 4;
    int s = 0;
#pragma unroll
    for (int k = 0; k < 4; ++k)
        if (i0 + k < n) s += deg[i0 + k];
    red[tid] = s;
    __syncthreads();
    for (int off = 128; off; off >>= 1) {
        if (tid < off) red[tid] += red[tid + off];
        __syncthreads();
    }
    if (tid == 0) bsum[b] = red[0];
}

__global__ __launch_bounds__(256) void k_scanbsums(const int* __restrict__ bsum, int* __restrict__ bofs, int nb) {
    __shared__ int tmp[256];
    int tid = threadIdx.x;
    int v = (tid < nb) ? bsum[tid] : 0;
    tmp[tid] = v;
    __syncthreads();
    for (int off = 1; off < 256; off <<= 1) {
        int t = (tid >= off) ? tmp[tid - off] : 0;
        __syncthreads();
        tmp[tid] += t;
        __syncthreads();
    }
    if (tid < nb) bofs[tid] = tmp[tid] - v;  // exclusive
}

__global__ __launch_bounds__(256) void k_scan_apply(const int* __restrict__ deg, const int* __restrict__ bofs,
                                                    int* __restrict__ rowptr, int* __restrict__ cursor,
                                                    float* __restrict__ dinv, int n) {
    __shared__ int tmp[256];
    int b = blockIdx.x, tid = threadIdx.x;
    int i0 = b * 1024 + tid * 4;
    int v[4];
#pragma unroll
    for (int k = 0; k < 4; ++k) v[k] = (i0 + k < n) ? deg[i0 + k] : 0;
    int tsum = v[0] + v[1] + v[2] + v[3];
    tmp[tid] = tsum;
    __syncthreads();
    for (int off = 1; off < 256; off <<= 1) {
        int t = (tid >= off) ? tmp[tid - off] : 0;
        __syncthreads();
        tmp[tid] += t;
        __syncthreads();
    }
    int p = tmp[tid] - tsum + bofs[b];  // exclusive prefix for this thread's first elem
#pragma unroll
    for (int k = 0; k < 4; ++k) {
        if (i0 + k < n) {
            rowptr[i0 + k] = p;
            cursor[i0 + k] = p;
            dinv[i0 + k] = rsqrtf((float)(v[k] + 1));  // +1 self loop
        }
        p += v[k];
    }
}

// ---------------- permute: group src indices by dst (counting sort) ----------------
__global__ void k_permute(const int* __restrict__ src, const int* __restrict__ dst,
                          int* __restrict__ cursor, int* __restrict__ esrc, int E) {
    int i = blockIdx.x * blockDim.x + threadIdx.x;
    int stride = gridDim.x * blockDim.x;
    for (int e = i; e < E; e += stride) {
        int d = dst[e];
        int pos = atomicAdd(&cursor[d], 1);
        esrc[pos] = src[e];
    }
}
// after k_permute: cursor[i] == rowptr[i] + indeg[i]  (i.e. row end)

// ---------------- GEMM1: g1 = dinv ⊙ (x @ W1^T) ----------------
__global__ __launch_bounds__(256) void k_gemm1(const float* __restrict__ x,
                                               const float* __restrict__ W1,
                                               const float* __restrict__ dinv,
                                               float* __restrict__ g1, int n) {
    __shared__ float As[16][68];
    __shared__ float Bs[16][132];
    const int tid = threadIdx.x;
    const int row0 = blockIdx.x * 64;
    const int tx = tid & 31, ty = tid >> 5;
    float acc[8][4] = {};
    for (int k0 = 0; k0 < 128; k0 += 16) {
        {
            int r = tid >> 2;
            int kk4 = (tid & 3) * 4;
            int grow = row0 + r;
            float4 v = make_float4(0.f, 0.f, 0.f, 0.f);
            if (grow < n) v = *(const float4*)&x[(size_t)grow * 128 + k0 + kk4];
            As[kk4 + 0][r] = v.x; As[kk4 + 1][r] = v.y;
            As[kk4 + 2][r] = v.z; As[kk4 + 3][r] = v.w;
        }
        {
            int j = tid >> 1;
            int kb = (tid & 1) * 8;
            const float* wp = &W1[(size_t)j * 128 + k0 + kb];
            float4 v0 = *(const float4*)wp;
            float4 v1 = *(const float4*)(wp + 4);
            Bs[kb + 0][j] = v0.x; Bs[kb + 1][j] = v0.y; Bs[kb + 2][j] = v0.z; Bs[kb + 3][j] = v0.w;
            Bs[kb + 4][j] = v1.x; Bs[kb + 5][j] = v1.y; Bs[kb + 6][j] = v1.z; Bs[kb + 7][j] = v1.w;
        }
        __syncthreads();
#pragma unroll
        for (int kk = 0; kk < 16; ++kk) {
            float4 a0 = *(const float4*)&As[kk][ty * 8];
            float4 a1 = *(const float4*)&As[kk][ty * 8 + 4];
            float4 b  = *(const float4*)&Bs[kk][tx * 4];
            float a[8] = {a0.x, a0.y, a0.z, a0.w, a1.x, a1.y, a1.z, a1.w};
            float bb[4] = {b.x, b.y, b.z, b.w};
#pragma unroll
            for (int r = 0; r < 8; ++r)
#pragma unroll
                for (int c = 0; c < 4; ++c) acc[r][c] = fmaf(a[r], bb[c], acc[r][c]);
        }
        __syncthreads();
    }
#pragma unroll
    for (int r = 0; r < 8; ++r) {
        int grow = row0 + ty * 8 + r;
        if (grow < n) {
            float di = dinv[grow];
            float4 v = make_float4(acc[r][0] * di, acc[r][1] * di, acc[r][2] * di, acc[r][3] * di);
            *(float4*)&g1[(size_t)grow * 128 + tx * 4] = v;
        }
    }
}

// ---------------- pull1: h1[d] = dinv[d]*(g1[d] + sum g1[src]) + b1 ; BN stats ----------------
__global__ __launch_bounds__(256) void k_pull1(const int* __restrict__ rowptr, const int* __restrict__ rowend,
                                               const int* __restrict__ esrc, const float* __restrict__ g,
                                               const float* __restrict__ dinv, const float* __restrict__ b1,
                                               float* __restrict__ h1, float* __restrict__ stats, int n) {
    __shared__ float2 sSum[4][64];
    __shared__ float2 sSq[4][64];
    const int wid = threadIdx.x >> 6, lane = threadIdx.x & 63;
    const int gw = blockIdx.x * 4 + wid;
    const int nw = gridDim.x * 4;
    const float2 bias = *(const float2*)&b1[lane * 2];
    float2 psum = {0.f, 0.f}, psq = {0.f, 0.f};
    for (int node = gw; node < n; node += nw) {
        float2 acc = *(const float2*)&g[(size_t)node * 128 + lane * 2];  // self loop
        const int b = rowptr[node], e = rowend[node];
        for (int j = b; j < e; ++j) {
            int s = esrc[j];
            const float2 v = *(const float2*)&g[(size_t)s * 128 + lane * 2];
            acc.x += v.x;
            acc.y += v.y;
        }
        const float di = dinv[node];
        float2 hv = {fmaf(acc.x, di, bias.x), fmaf(acc.y, di, bias.y)};
        *(float2*)&h1[(size_t)node * 128 + lane * 2] = hv;
        psum.x += hv.x; psum.y += hv.y;
        psq.x = fmaf(hv.x, hv.x, psq.x);
        psq.y = fmaf(hv.y, hv.y, psq.y);
    }
    sSum[wid][lane] = psum;
    sSq[wid][lane] = psq;
    __syncthreads();
    if (threadIdx.x < 64) {
        float2 a = sSum[0][lane], b = sSum[1][lane], c = sSum[2][lane], d = sSum[3][lane];
        atomicAdd(&stats[lane * 2 + 0], a.x + b.x + c.x + d.x);
        atomicAdd(&stats[lane * 2 + 1], a.y + b.y + c.y + d.y);
        a = sSq[0][lane]; b = sSq[1][lane]; c = sSq[2][lane]; d = sSq[3][lane];
        atomicAdd(&stats[128 + lane * 2 + 0], a.x + b.x + c.x + d.x);
        atomicAdd(&stats[128 + lane * 2 + 1], a.y + b.y + c.y + d.y);
    }
}

// ---------------- BN scale/shift from sums ----------------
__global__ void k_bnfinal(float* __restrict__ stats, const float* __restrict__ gamma,
                          const float* __restrict__ beta, int n) {
    int f = threadIdx.x;  // 128 threads
    float inv_n = 1.f / (float)n;
    float mean = stats[f] * inv_n;
    float var = stats[128 + f] * inv_n - mean * mean;
    float sc = gamma[f] * rsqrtf(var + BN_EPS);
    stats[256 + f] = sc;
    stats[384 + f] = fmaf(-mean, sc, beta[f]);
}

// ---------------- GEMM2: g2 = dinv ⊙ (relu(BN(h1)) @ W2^T) ----------------
__global__ __launch_bounds__(256) void k_gemm2(const float* __restrict__ h1,
                                               const float* __restrict__ W2,
                                               const float* __restrict__ dinv,
                                               const float* __restrict__ stats,
                                               float* __restrict__ g2, int n) {
    __shared__ float As[16][68];
    __shared__ float Bs[16][68];
    __shared__ float sSc[128], sSh[128];
    const int tid = threadIdx.x;
    if (tid < 128) {
        sSc[tid] = stats[256 + tid];
        sSh[tid] = stats[384 + tid];
    }
    const int row0 = blockIdx.x * 64;
    const int tx = tid & 15, ty = tid >> 4;
    float acc[4][4] = {};
    __syncthreads();
    for (int k0 = 0; k0 < 128; k0 += 16) {
        {
            int r = tid >> 2;
            int kk4 = (tid & 3) * 4;
            int grow = row0 + r;
            float4 v = make_float4(0.f, 0.f, 0.f, 0.f);
            if (grow < n) v = *(const float4*)&h1[(size_t)grow * 128 + k0 + kk4];
            int k = k0 + kk4;
            As[kk4 + 0][r] = fmaxf(fmaf(v.x, sSc[k + 0], sSh[k + 0]), 0.f);
            As[kk4 + 1][r] = fmaxf(fmaf(v.y, sSc[k + 1], sSh[k + 1]), 0.f);
            As[kk4 + 2][r] = fmaxf(fmaf(v.z, sSc[k + 2], sSh[k + 2]), 0.f);
            As[kk4 + 3][r] = fmaxf(fmaf(v.w, sSc[k + 3], sSh[k + 3]), 0.f);
        }
        {
            int j = tid >> 2;
            int kb = (tid & 3) * 4;
            float4 v = *(const float4*)&W2[(size_t)j * 128 + k0 + kb];
            Bs[kb + 0][j] = v.x; Bs[kb + 1][j] = v.y;
            Bs[kb + 2][j] = v.z; Bs[kb + 3][j] = v.w;
        }
        __syncthreads();
#pragma unroll
        for (int kk = 0; kk < 16; ++kk) {
            float4 a = *(const float4*)&As[kk][ty * 4];
            float4 b = *(const float4*)&Bs[kk][tx * 4];
            float aa[4] = {a.x, a.y, a.z, a.w};
            float bb[4] = {b.x, b.y, b.z, b.w};
#pragma unroll
            for (int r = 0; r < 4; ++r)
#pragma unroll
                for (int c = 0; c < 4; ++c) acc[r][c] = fmaf(aa[r], bb[c], acc[r][c]);
        }
        __syncthreads();
    }
#pragma unroll
    for (int r = 0; r < 4; ++r) {
        int grow = row0 + ty * 4 + r;
        if (grow < n) {
            float di = dinv[grow];
            float4 v = make_float4(acc[r][0] * di, acc[r][1] * di, acc[r][2] * di, acc[r][3] * di);
            *(float4*)&g2[(size_t)grow * 64 + tx * 4] = v;
        }
    }
}

// ---------------- pull2: out[d] = dinv[d]*(g2[d] + sum g2[src]) + b2 ----------------
__global__ __launch_bounds__(256) void k_pull2(const int* __restrict__ rowptr, const int* __restrict__ rowend,
                                               const int* __restrict__ esrc, const float* __restrict__ g,
                                               const float* __restrict__ dinv, const float* __restrict__ b2,
                                               float* __restrict__ out, int n) {
    const int wid = threadIdx.x >> 6, lane = threadIdx.x & 63;
    const int gw = blockIdx.x * 4 + wid;
    const int nw = gridDim.x * 4;
    const float bias = b2[lane];
    for (int node = gw; node < n; node += nw) {
        float acc = g[(size_t)node * 64 + lane];  // self loop
        const int b = rowptr[node], e = rowend[node];
        for (int j = b; j < e; ++j) {
            int s = esrc[j];
            acc += g[(size_t)s * 64 + lane];
        }
        out[(size_t)node * 64 + lane] = fmaf(acc, dinv[node], bias);
    }
}

extern "C" void kernel_launch(void* const* d_in, const int* in_sizes, int n_in,
                              void* d_out, int out_size, void* d_ws, size_t ws_size,
                              hipStream_t stream) {
    const float* x     = (const float*)d_in[0];
    const int*   ei    = (const int*)d_in[1];
    const float* W1    = (const float*)d_in[2];
    const float* b1    = (const float*)d_in[3];
    const float* gamma = (const float*)d_in[4];
    const float* beta  = (const float*)d_in[5];
    const float* W2    = (const float*)d_in[6];
    const float* b2    = (const float*)d_in[7];
    float* out = (float*)d_out;

    const int n = in_sizes[0] / 128;
    const int E = in_sizes[1] / 2;
    const int* src = ei;
    const int* dst = ei + E;

    char* ws = (char*)d_ws;
    const int Np = (n + 255) & ~255;
    const int Ep = (E + 3) & ~3;
    int*   deg    = (int*)ws;
    int*   rowptr = deg + Np;
    int*   cursor = rowptr + Np;
    float* dinv   = (float*)(cursor + Np);
    float* stats  = dinv + Np;              // [0,128)sum [128,256)sumsq [256,384)scale [384,512)shift
    int*   bsum   = (int*)(stats + 512);    // 1024
    int*   bofs   = bsum + 1024;            // 1024
    int*   esrc   = bofs + 1024;            // Ep
    float* g1     = (float*)(esrc + Ep);    // n*128
    float* h1     = g1 + (size_t)n * 128;   // n*128
    float* g2     = g1;                     // reuse (g1 dead after pull1)

    const int nb = (n + 255) / 256;
    const int nscan = (n + 1023) / 1024;    // <= 256 for n <= 262144
    const int gb = (n + 63) / 64;

    hipLaunchKernelGGL(k_init, dim3(nb), dim3(256), 0, stream, deg, stats, n);
    hipLaunchKernelGGL(k_count, dim3(1024), dim3(256), 0, stream, dst, deg, E);
    hipLaunchKernelGGL(k_blocksum, dim3(nscan), dim3(256), 0, stream, deg, bsum, n);
    hipLaunchKernelGGL(k_scanbsums, dim3(1), dim3(256), 0, stream, bsum, bofs, nscan);
    hipLaunchKernelGGL(k_scan_apply, dim3(nscan), dim3(256), 0, stream, deg, bofs, rowptr, cursor, dinv, n);

    hipLaunchKernelGGL(k_gemm1, dim3(gb), dim3(256), 0, stream, x, W1, dinv, g1, n);
    hipLaunchKernelGGL(k_permute, dim3(1024), dim3(256), 0, stream, src, dst, cursor, esrc, E);
    hipLaunchKernelGGL(k_pull1, dim3(1024), dim3(256), 0, stream, rowptr, cursor, esrc, g1, dinv, b1, h1, stats, n);
    hipLaunchKernelGGL(k_bnfinal, dim3(1), dim3(128), 0, stream, stats, gamma, beta, n);

    hipLaunchKernelGGL(k_gemm2, dim3(gb), dim3(256), 0, stream, h1, W2, dinv, stats, g2, n);
    hipLaunchKernelGGL(k_pull2, dim3(1024), dim3(256), 0, stream, rowptr, cursor, esrc, g2, dinv, b2, out, n);
}

// Round 3
// 561.094 us; speedup vs baseline: 3.2827x; 1.4733x over previous
//
#include <hip/hip_runtime.h>

constexpr float BN_EPS = 1e-5f;

// ---------------- init: zero deg counters + BN stat accumulators ----------------
__global__ void k_init(int* __restrict__ deg, float* __restrict__ stats, int n) {
    int i = blockIdx.x * blockDim.x + threadIdx.x;
    if (i < n) deg[i] = 0;
    if (blockIdx.x == 0 && threadIdx.x < 256) stats[threadIdx.x] = 0.f;
}

// ---------------- count in-degree over edges (excl self loops) ----------------
__global__ void k_count(const int* __restrict__ dst, int* __restrict__ deg, int E) {
    int i = blockIdx.x * blockDim.x + threadIdx.x;
    int stride = gridDim.x * blockDim.x;
    for (int e = i; e < E; e += stride) atomicAdd(&deg[dst[e]], 1);
}

// ---------------- hierarchical exclusive scan of deg -> rowptr (chunk = 1024) ----------------
__global__ __launch_bounds__(256) void k_blocksum(const int* __restrict__ deg, int* __restrict__ bsum, int n) {
    __shared__ int red[256];
    int b = blockIdx.x, tid = threadIdx.x;
    int i0 = b * 1024 + tid * 4;
    int s = 0;
#pragma unroll
    for (int k = 0; k < 4; ++k)
        if (i0 + k < n) s += deg[i0 + k];
    red[tid] = s;
    __syncthreads();
    for (int off = 128; off; off >>= 1) {
        if (tid < off) red[tid] += red[tid + off];
        __syncthreads();
    }
    if (tid == 0) bsum[b] = red[0];
}

__global__ __launch_bounds__(256) void k_scanbsums(const int* __restrict__ bsum, int* __restrict__ bofs, int nb) {
    __shared__ int tmp[256];
    int tid = threadIdx.x;
    int v = (tid < nb) ? bsum[tid] : 0;
    tmp[tid] = v;
    __syncthreads();
    for (int off = 1; off < 256; off <<= 1) {
        int t = (tid >= off) ? tmp[tid - off] : 0;
        __syncthreads();
        tmp[tid] += t;
        __syncthreads();
    }
    if (tid < nb) bofs[tid] = tmp[tid] - v;  // exclusive
}

__global__ __launch_bounds__(256) void k_scan_apply(const int* __restrict__ deg, const int* __restrict__ bofs,
                                                    int* __restrict__ rowptr, int* __restrict__ cursor,
                                                    float* __restrict__ dinv, int n) {
    __shared__ int tmp[256];
    int b = blockIdx.x, tid = threadIdx.x;
    int i0 = b * 1024 + tid * 4;
    int v[4];
#pragma unroll
    for (int k = 0; k < 4; ++k) v[k] = (i0 + k < n) ? deg[i0 + k] : 0;
    int tsum = v[0] + v[1] + v[2] + v[3];
    tmp[tid] = tsum;
    __syncthreads();
    for (int off = 1; off < 256; off <<= 1) {
        int t = (tid >= off) ? tmp[tid - off] : 0;
        __syncthreads();
        tmp[tid] += t;
        __syncthreads();
    }
    int p = tmp[tid] - tsum + bofs[b];
#pragma unroll
    for (int k = 0; k < 4; ++k) {
        if (i0 + k < n) {
            rowptr[i0 + k] = p;
            cursor[i0 + k] = p;
            dinv[i0 + k] = rsqrtf((float)(v[k] + 1));  // +1 self loop
        }
        p += v[k];
    }
}

// ---------------- permute: group src indices by dst (counting sort) ----------------
__global__ void k_permute(const int* __restrict__ src, const int* __restrict__ dst,
                          int* __restrict__ cursor, int* __restrict__ esrc, int E) {
    int i = blockIdx.x * blockDim.x + threadIdx.x;
    int stride = gridDim.x * blockDim.x;
    for (int e = i; e < E; e += stride) {
        int d = dst[e];
        int pos = atomicAdd(&cursor[d], 1);
        esrc[pos] = src[e];
    }
}

// ---------------- GEMM1: g1 = dinv ⊙ (x @ W1^T) ----------------
__global__ __launch_bounds__(256) void k_gemm1(const float* __restrict__ x,
                                               const float* __restrict__ W1,
                                               const float* __restrict__ dinv,
                                               float* __restrict__ g1, int n) {
    __shared__ float As[16][68];
    __shared__ float Bs[16][132];
    const int tid = threadIdx.x;
    const int row0 = blockIdx.x * 64;
    const int tx = tid & 31, ty = tid >> 5;
    float acc[8][4] = {};
    for (int k0 = 0; k0 < 128; k0 += 16) {
        {
            int r = tid >> 2;
            int kk4 = (tid & 3) * 4;
            int grow = row0 + r;
            float4 v = make_float4(0.f, 0.f, 0.f, 0.f);
            if (grow < n) v = *(const float4*)&x[(size_t)grow * 128 + k0 + kk4];
            As[kk4 + 0][r] = v.x; As[kk4 + 1][r] = v.y;
            As[kk4 + 2][r] = v.z; As[kk4 + 3][r] = v.w;
        }
        {
            int j = tid >> 1;
            int kb = (tid & 1) * 8;
            const float* wp = &W1[(size_t)j * 128 + k0 + kb];
            float4 v0 = *(const float4*)wp;
            float4 v1 = *(const float4*)(wp + 4);
            Bs[kb + 0][j] = v0.x; Bs[kb + 1][j] = v0.y; Bs[kb + 2][j] = v0.z; Bs[kb + 3][j] = v0.w;
            Bs[kb + 4][j] = v1.x; Bs[kb + 5][j] = v1.y; Bs[kb + 6][j] = v1.z; Bs[kb + 7][j] = v1.w;
        }
        __syncthreads();
#pragma unroll
        for (int kk = 0; kk < 16; ++kk) {
            float4 a0 = *(const float4*)&As[kk][ty * 8];
            float4 a1 = *(const float4*)&As[kk][ty * 8 + 4];
            float4 b  = *(const float4*)&Bs[kk][tx * 4];
            float a[8] = {a0.x, a0.y, a0.z, a0.w, a1.x, a1.y, a1.z, a1.w};
            float bb[4] = {b.x, b.y, b.z, b.w};
#pragma unroll
            for (int r = 0; r < 8; ++r)
#pragma unroll
                for (int c = 0; c < 4; ++c) acc[r][c] = fmaf(a[r], bb[c], acc[r][c]);
        }
        __syncthreads();
    }
#pragma unroll
    for (int r = 0; r < 8; ++r) {
        int grow = row0 + ty * 8 + r;
        if (grow < n) {
            float di = dinv[grow];
            float4 v = make_float4(acc[r][0] * di, acc[r][1] * di, acc[r][2] * di, acc[r][3] * di);
            *(float4*)&g1[(size_t)grow * 128 + tx * 4] = v;
        }
    }
}

// ---------------- pull1: h1[d] = dinv[d]*(g1[d] + sum g1[src]) + b1 ; BN stats ----------------
__global__ __launch_bounds__(256) void k_pull1(const int* __restrict__ rowptr, const int* __restrict__ rowend,
                                               const int* __restrict__ esrc, const float* __restrict__ g,
                                               const float* __restrict__ dinv, const float* __restrict__ b1,
                                               float* __restrict__ h1, float* __restrict__ stats, int n) {
    __shared__ float2 sSum[4][64];
    __shared__ float2 sSq[4][64];
    const int wid = threadIdx.x >> 6, lane = threadIdx.x & 63;
    const int gw = blockIdx.x * 4 + wid;
    const int nw = gridDim.x * 4;
    const float2 bias = *(const float2*)&b1[lane * 2];
    float2 psum = {0.f, 0.f}, psq = {0.f, 0.f};
    for (int node = gw; node < n; node += nw) {
        const int b = rowptr[node], e = rowend[node];
        // 4 independent accumulators -> 4 row-gathers in flight
        float2 a0 = *(const float2*)&g[(size_t)node * 128 + lane * 2];  // self loop
        float2 a1 = {0.f, 0.f}, a2 = {0.f, 0.f}, a3 = {0.f, 0.f};
        int j = b;
        for (; j + 4 <= e; j += 4) {
            int s0 = esrc[j + 0], s1 = esrc[j + 1], s2 = esrc[j + 2], s3 = esrc[j + 3];
            float2 v0 = *(const float2*)&g[(size_t)s0 * 128 + lane * 2];
            float2 v1 = *(const float2*)&g[(size_t)s1 * 128 + lane * 2];
            float2 v2 = *(const float2*)&g[(size_t)s2 * 128 + lane * 2];
            float2 v3 = *(const float2*)&g[(size_t)s3 * 128 + lane * 2];
            a0.x += v0.x; a0.y += v0.y;
            a1.x += v1.x; a1.y += v1.y;
            a2.x += v2.x; a2.y += v2.y;
            a3.x += v3.x; a3.y += v3.y;
        }
        for (; j < e; ++j) {
            int s = esrc[j];
            float2 v = *(const float2*)&g[(size_t)s * 128 + lane * 2];
            a0.x += v.x; a0.y += v.y;
        }
        float2 acc = {(a0.x + a1.x) + (a2.x + a3.x), (a0.y + a1.y) + (a2.y + a3.y)};
        const float di = dinv[node];
        float2 hv = {fmaf(acc.x, di, bias.x), fmaf(acc.y, di, bias.y)};
        *(float2*)&h1[(size_t)node * 128 + lane * 2] = hv;
        psum.x += hv.x; psum.y += hv.y;
        psq.x = fmaf(hv.x, hv.x, psq.x);
        psq.y = fmaf(hv.y, hv.y, psq.y);
    }
    sSum[wid][lane] = psum;
    sSq[wid][lane] = psq;
    __syncthreads();
    if (threadIdx.x < 64) {
        float2 a = sSum[0][lane], b = sSum[1][lane], c = sSum[2][lane], d = sSum[3][lane];
        atomicAdd(&stats[lane * 2 + 0], a.x + b.x + c.x + d.x);
        atomicAdd(&stats[lane * 2 + 1], a.y + b.y + c.y + d.y);
        a = sSq[0][lane]; b = sSq[1][lane]; c = sSq[2][lane]; d = sSq[3][lane];
        atomicAdd(&stats[128 + lane * 2 + 0], a.x + b.x + c.x + d.x);
        atomicAdd(&stats[128 + lane * 2 + 1], a.y + b.y + c.y + d.y);
    }
}

// ---------------- BN scale/shift from sums ----------------
__global__ void k_bnfinal(float* __restrict__ stats, const float* __restrict__ gamma,
                          const float* __restrict__ beta, int n) {
    int f = threadIdx.x;  // 128 threads
    float inv_n = 1.f / (float)n;
    float mean = stats[f] * inv_n;
    float var = stats[128 + f] * inv_n - mean * mean;
    float sc = gamma[f] * rsqrtf(var + BN_EPS);
    stats[256 + f] = sc;
    stats[384 + f] = fmaf(-mean, sc, beta[f]);
}

// ---------------- GEMM2: g2 = dinv ⊙ (relu(BN(h1)) @ W2^T) ----------------
__global__ __launch_bounds__(256) void k_gemm2(const float* __restrict__ h1,
                                               const float* __restrict__ W2,
                                               const float* __restrict__ dinv,
                                               const float* __restrict__ stats,
                                               float* __restrict__ g2, int n) {
    __shared__ float As[16][68];
    __shared__ float Bs[16][68];
    __shared__ float sSc[128], sSh[128];
    const int tid = threadIdx.x;
    if (tid < 128) {
        sSc[tid] = stats[256 + tid];
        sSh[tid] = stats[384 + tid];
    }
    const int row0 = blockIdx.x * 64;
    const int tx = tid & 15, ty = tid >> 4;
    float acc[4][4] = {};
    __syncthreads();
    for (int k0 = 0; k0 < 128; k0 += 16) {
        {
            int r = tid >> 2;
            int kk4 = (tid & 3) * 4;
            int grow = row0 + r;
            float4 v = make_float4(0.f, 0.f, 0.f, 0.f);
            if (grow < n) v = *(const float4*)&h1[(size_t)grow * 128 + k0 + kk4];
            int k = k0 + kk4;
            As[kk4 + 0][r] = fmaxf(fmaf(v.x, sSc[k + 0], sSh[k + 0]), 0.f);
            As[kk4 + 1][r] = fmaxf(fmaf(v.y, sSc[k + 1], sSh[k + 1]), 0.f);
            As[kk4 + 2][r] = fmaxf(fmaf(v.z, sSc[k + 2], sSh[k + 2]), 0.f);
            As[kk4 + 3][r] = fmaxf(fmaf(v.w, sSc[k + 3], sSh[k + 3]), 0.f);
        }
        {
            int j = tid >> 2;
            int kb = (tid & 3) * 4;
            float4 v = *(const float4*)&W2[(size_t)j * 128 + k0 + kb];
            Bs[kb + 0][j] = v.x; Bs[kb + 1][j] = v.y;
            Bs[kb + 2][j] = v.z; Bs[kb + 3][j] = v.w;
        }
        __syncthreads();
#pragma unroll
        for (int kk = 0; kk < 16; ++kk) {
            float4 a = *(const float4*)&As[kk][ty * 4];
            float4 b = *(const float4*)&Bs[kk][tx * 4];
            float aa[4] = {a.x, a.y, a.z, a.w};
            float bb[4] = {b.x, b.y, b.z, b.w};
#pragma unroll
            for (int r = 0; r < 4; ++r)
#pragma unroll
                for (int c = 0; c < 4; ++c) acc[r][c] = fmaf(aa[r], bb[c], acc[r][c]);
        }
        __syncthreads();
    }
#pragma unroll
    for (int r = 0; r < 4; ++r) {
        int grow = row0 + ty * 4 + r;
        if (grow < n) {
            float di = dinv[grow];
            float4 v = make_float4(acc[r][0] * di, acc[r][1] * di, acc[r][2] * di, acc[r][3] * di);
            *(float4*)&g2[(size_t)grow * 64 + tx * 4] = v;
        }
    }
}

// ---------------- pull2: out[d] = dinv[d]*(g2[d] + sum g2[src]) + b2 ----------------
__global__ __launch_bounds__(256) void k_pull2(const int* __restrict__ rowptr, const int* __restrict__ rowend,
                                               const int* __restrict__ esrc, const float* __restrict__ g,
                                               const float* __restrict__ dinv, const float* __restrict__ b2,
                                               float* __restrict__ out, int n) {
    const int wid = threadIdx.x >> 6, lane = threadIdx.x & 63;
    const int gw = blockIdx.x * 4 + wid;
    const int nw = gridDim.x * 4;
    const float bias = b2[lane];
    for (int node = gw; node < n; node += nw) {
        const int b = rowptr[node], e = rowend[node];
        float a0 = g[(size_t)node * 64 + lane];  // self loop
        float a1 = 0.f, a2 = 0.f, a3 = 0.f;
        int j = b;
        for (; j + 4 <= e; j += 4) {
            int s0 = esrc[j + 0], s1 = esrc[j + 1], s2 = esrc[j + 2], s3 = esrc[j + 3];
            float v0 = g[(size_t)s0 * 64 + lane];
            float v1 = g[(size_t)s1 * 64 + lane];
            float v2 = g[(size_t)s2 * 64 + lane];
            float v3 = g[(size_t)s3 * 64 + lane];
            a0 += v0; a1 += v1; a2 += v2; a3 += v3;
        }
        for (; j < e; ++j) a0 += g[(size_t)esrc[j] * 64 + lane];
        out[(size_t)node * 64 + lane] = fmaf((a0 + a1) + (a2 + a3), dinv[node], bias);
    }
}

extern "C" void kernel_launch(void* const* d_in, const int* in_sizes, int n_in,
                              void* d_out, int out_size, void* d_ws, size_t ws_size,
                              hipStream_t stream) {
    const float* x     = (const float*)d_in[0];
    const int*   ei    = (const int*)d_in[1];
    const float* W1    = (const float*)d_in[2];
    const float* b1    = (const float*)d_in[3];
    const float* gamma = (const float*)d_in[4];
    const float* beta  = (const float*)d_in[5];
    const float* W2    = (const float*)d_in[6];
    const float* b2    = (const float*)d_in[7];
    float* out = (float*)d_out;

    const int n = in_sizes[0] / 128;
    const int E = in_sizes[1] / 2;
    const int* src = ei;
    const int* dst = ei + E;

    char* ws = (char*)d_ws;
    const int Np = (n + 255) & ~255;
    const int Ep = (E + 3) & ~3;
    int*   deg    = (int*)ws;
    int*   rowptr = deg + Np;
    int*   cursor = rowptr + Np;
    float* dinv   = (float*)(cursor + Np);
    float* stats  = dinv + Np;
    int*   bsum   = (int*)(stats + 512);
    int*   bofs   = bsum + 1024;
    int*   esrc   = bofs + 1024;
    float* g1     = (float*)(esrc + Ep);
    float* h1     = g1 + (size_t)n * 128;
    float* g2     = g1;  // reuse (g1 dead after pull1)

    const int nb = (n + 255) / 256;
    const int nscan = (n + 1023) / 1024;
    const int gb = (n + 63) / 64;

    hipLaunchKernelGGL(k_init, dim3(nb), dim3(256), 0, stream, deg, stats, n);
    hipLaunchKernelGGL(k_count, dim3(1024), dim3(256), 0, stream, dst, deg, E);
    hipLaunchKernelGGL(k_blocksum, dim3(nscan), dim3(256), 0, stream, deg, bsum, n);
    hipLaunchKernelGGL(k_scanbsums, dim3(1), dim3(256), 0, stream, bsum, bofs, nscan);
    hipLaunchKernelGGL(k_scan_apply, dim3(nscan), dim3(256), 0, stream, deg, bofs, rowptr, cursor, dinv, n);

    hipLaunchKernelGGL(k_gemm1, dim3(gb), dim3(256), 0, stream, x, W1, dinv, g1, n);
    hipLaunchKernelGGL(k_permute, dim3(1024), dim3(256), 0, stream, src, dst, cursor, esrc, E);
    hipLaunchKernelGGL(k_pull1, dim3(2048), dim3(256), 0, stream, rowptr, cursor, esrc, g1, dinv, b1, h1, stats, n);
    hipLaunchKernelGGL(k_bnfinal, dim3(1), dim3(128), 0, stream, stats, gamma, beta, n);

    hipLaunchKernelGGL(k_gemm2, dim3(gb), dim3(256), 0, stream, h1, W2, dinv, stats, g2, n);
    hipLaunchKernelGGL(k_pull2, dim3(2048), dim3(256), 0, stream, rowptr, cursor, esrc, g2, dinv, b2, out, n);
}

// Round 4
// 507.174 us; speedup vs baseline: 3.6317x; 1.1063x over previous
//
#include <hip/hip_runtime.h>

constexpr float BN_EPS = 1e-5f;

// bf16 helpers (bit ops; RNE on pack)
__device__ inline float2 bf2x2(unsigned int v) {
    union { unsigned int i; float f; } a, b;
    a.i = v << 16;
    b.i = v & 0xFFFF0000u;
    return make_float2(a.f, b.f);
}
__device__ inline float bf2f(unsigned short u) {
    union { unsigned int i; float f; } a;
    a.i = ((unsigned int)u) << 16;
    return a.f;
}
__device__ inline unsigned short f2bf(float f) {
    union { float f; unsigned int i; } c;
    c.f = f;
    unsigned int i = c.i;
    return (unsigned short)((i + 0x7FFFu + ((i >> 16) & 1u)) >> 16);
}

// ---------------- init: zero deg counters + BN stat accumulators ----------------
__global__ void k_init(int* __restrict__ deg, float* __restrict__ stats, int n) {
    int i = blockIdx.x * blockDim.x + threadIdx.x;
    if (i < n) deg[i] = 0;
    if (blockIdx.x == 0 && threadIdx.x < 256) stats[threadIdx.x] = 0.f;
}

// ---------------- count in-degree over edges (excl self loops) ----------------
__global__ void k_count(const int* __restrict__ dst, int* __restrict__ deg, int E) {
    int i = blockIdx.x * blockDim.x + threadIdx.x;
    int stride = gridDim.x * blockDim.x;
    for (int e = i; e < E; e += stride) atomicAdd(&deg[dst[e]], 1);
}

// ---------------- hierarchical exclusive scan of deg -> rowptr (chunk = 1024) ----------------
__global__ __launch_bounds__(256) void k_blocksum(const int* __restrict__ deg, int* __restrict__ bsum, int n) {
    __shared__ int red[256];
    int b = blockIdx.x, tid = threadIdx.x;
    int i0 = b * 1024 + tid * 4;
    int s = 0;
#pragma unroll
    for (int k = 0; k < 4; ++k)
        if (i0 + k < n) s += deg[i0 + k];
    red[tid] = s;
    __syncthreads();
    for (int off = 128; off; off >>= 1) {
        if (tid < off) red[tid] += red[tid + off];
        __syncthreads();
    }
    if (tid == 0) bsum[b] = red[0];
}

__global__ __launch_bounds__(256) void k_scanbsums(const int* __restrict__ bsum, int* __restrict__ bofs, int nb) {
    __shared__ int tmp[256];
    int tid = threadIdx.x;
    int v = (tid < nb) ? bsum[tid] : 0;
    tmp[tid] = v;
    __syncthreads();
    for (int off = 1; off < 256; off <<= 1) {
        int t = (tid >= off) ? tmp[tid - off] : 0;
        __syncthreads();
        tmp[tid] += t;
        __syncthreads();
    }
    if (tid < nb) bofs[tid] = tmp[tid] - v;  // exclusive
}

__global__ __launch_bounds__(256) void k_scan_apply(const int* __restrict__ deg, const int* __restrict__ bofs,
                                                    int* __restrict__ rowptr, int* __restrict__ cursor,
                                                    float* __restrict__ dinv, int n) {
    __shared__ int tmp[256];
    int b = blockIdx.x, tid = threadIdx.x;
    int i0 = b * 1024 + tid * 4;
    int v[4];
#pragma unroll
    for (int k = 0; k < 4; ++k) v[k] = (i0 + k < n) ? deg[i0 + k] : 0;
    int tsum = v[0] + v[1] + v[2] + v[3];
    tmp[tid] = tsum;
    __syncthreads();
    for (int off = 1; off < 256; off <<= 1) {
        int t = (tid >= off) ? tmp[tid - off] : 0;
        __syncthreads();
        tmp[tid] += t;
        __syncthreads();
    }
    int p = tmp[tid] - tsum + bofs[b];
#pragma unroll
    for (int k = 0; k < 4; ++k) {
        if (i0 + k < n) {
            rowptr[i0 + k] = p;
            cursor[i0 + k] = p;
            dinv[i0 + k] = rsqrtf((float)(v[k] + 1));  // +1 self loop
        }
        p += v[k];
    }
}

// ---------------- permute: group src indices by dst (counting sort) ----------------
__global__ void k_permute(const int* __restrict__ src, const int* __restrict__ dst,
                          int* __restrict__ cursor, int* __restrict__ esrc, int E) {
    int i = blockIdx.x * blockDim.x + threadIdx.x;
    int stride = gridDim.x * blockDim.x;
    for (int e = i; e < E; e += stride) {
        int d = dst[e];
        int pos = atomicAdd(&cursor[d], 1);
        esrc[pos] = src[e];
    }
}

// ---------------- GEMM1: g1 = bf16( dinv ⊙ (x @ W1^T) ) ----------------
__global__ __launch_bounds__(256) void k_gemm1(const float* __restrict__ x,
                                               const float* __restrict__ W1,
                                               const float* __restrict__ dinv,
                                               unsigned short* __restrict__ g1, int n) {
    __shared__ float As[16][68];
    __shared__ float Bs[16][132];
    const int tid = threadIdx.x;
    const int row0 = blockIdx.x * 64;
    const int tx = tid & 31, ty = tid >> 5;
    float acc[8][4] = {};
    for (int k0 = 0; k0 < 128; k0 += 16) {
        {
            int r = tid >> 2;
            int kk4 = (tid & 3) * 4;
            int grow = row0 + r;
            float4 v = make_float4(0.f, 0.f, 0.f, 0.f);
            if (grow < n) v = *(const float4*)&x[(size_t)grow * 128 + k0 + kk4];
            As[kk4 + 0][r] = v.x; As[kk4 + 1][r] = v.y;
            As[kk4 + 2][r] = v.z; As[kk4 + 3][r] = v.w;
        }
        {
            int j = tid >> 1;
            int kb = (tid & 1) * 8;
            const float* wp = &W1[(size_t)j * 128 + k0 + kb];
            float4 v0 = *(const float4*)wp;
            float4 v1 = *(const float4*)(wp + 4);
            Bs[kb + 0][j] = v0.x; Bs[kb + 1][j] = v0.y; Bs[kb + 2][j] = v0.z; Bs[kb + 3][j] = v0.w;
            Bs[kb + 4][j] = v1.x; Bs[kb + 5][j] = v1.y; Bs[kb + 6][j] = v1.z; Bs[kb + 7][j] = v1.w;
        }
        __syncthreads();
#pragma unroll
        for (int kk = 0; kk < 16; ++kk) {
            float4 a0 = *(const float4*)&As[kk][ty * 8];
            float4 a1 = *(const float4*)&As[kk][ty * 8 + 4];
            float4 b  = *(const float4*)&Bs[kk][tx * 4];
            float a[8] = {a0.x, a0.y, a0.z, a0.w, a1.x, a1.y, a1.z, a1.w};
            float bb[4] = {b.x, b.y, b.z, b.w};
#pragma unroll
            for (int r = 0; r < 8; ++r)
#pragma unroll
                for (int c = 0; c < 4; ++c) acc[r][c] = fmaf(a[r], bb[c], acc[r][c]);
        }
        __syncthreads();
    }
#pragma unroll
    for (int r = 0; r < 8; ++r) {
        int grow = row0 + ty * 8 + r;
        if (grow < n) {
            float di = dinv[grow];
            ushort4 u;
            u.x = f2bf(acc[r][0] * di);
            u.y = f2bf(acc[r][1] * di);
            u.z = f2bf(acc[r][2] * di);
            u.w = f2bf(acc[r][3] * di);
            *(ushort4*)&g1[(size_t)grow * 128 + tx * 4] = u;
        }
    }
}

// ---------------- pull1: h1[d] = dinv[d]*(g1[d] + sum g1[src]) + b1 ; BN stats ----------------
__global__ __launch_bounds__(256) void k_pull1(const int* __restrict__ rowptr, const int* __restrict__ rowend,
                                               const int* __restrict__ esrc, const unsigned short* __restrict__ g,
                                               const float* __restrict__ dinv, const float* __restrict__ b1,
                                               float* __restrict__ h1, float* __restrict__ stats, int n) {
    __shared__ float2 sSum[4][64];
    __shared__ float2 sSq[4][64];
    const int wid = threadIdx.x >> 6, lane = threadIdx.x & 63;
    const int gw = blockIdx.x * 4 + wid;
    const int nw = gridDim.x * 4;
    const float2 bias = *(const float2*)&b1[lane * 2];
    float2 psum = {0.f, 0.f}, psq = {0.f, 0.f};
    for (int node = gw; node < n; node += nw) {
        const int b = rowptr[node], e = rowend[node];
        // 8 independent accumulators -> 8 row-gathers in flight
        float2 a0 = bf2x2(*(const unsigned int*)&g[(size_t)node * 128 + lane * 2]);  // self loop
        float2 a1 = {0.f, 0.f}, a2 = {0.f, 0.f}, a3 = {0.f, 0.f};
        float2 a4 = {0.f, 0.f}, a5 = {0.f, 0.f}, a6 = {0.f, 0.f}, a7 = {0.f, 0.f};
        int j = b;
        for (; j + 8 <= e; j += 8) {
            int s0 = esrc[j + 0], s1 = esrc[j + 1], s2 = esrc[j + 2], s3 = esrc[j + 3];
            int s4 = esrc[j + 4], s5 = esrc[j + 5], s6 = esrc[j + 6], s7 = esrc[j + 7];
            unsigned int v0 = *(const unsigned int*)&g[(size_t)s0 * 128 + lane * 2];
            unsigned int v1 = *(const unsigned int*)&g[(size_t)s1 * 128 + lane * 2];
            unsigned int v2 = *(const unsigned int*)&g[(size_t)s2 * 128 + lane * 2];
            unsigned int v3 = *(const unsigned int*)&g[(size_t)s3 * 128 + lane * 2];
            unsigned int v4 = *(const unsigned int*)&g[(size_t)s4 * 128 + lane * 2];
            unsigned int v5 = *(const unsigned int*)&g[(size_t)s5 * 128 + lane * 2];
            unsigned int v6 = *(const unsigned int*)&g[(size_t)s6 * 128 + lane * 2];
            unsigned int v7 = *(const unsigned int*)&g[(size_t)s7 * 128 + lane * 2];
            float2 f0 = bf2x2(v0), f1 = bf2x2(v1), f2 = bf2x2(v2), f3 = bf2x2(v3);
            float2 f4 = bf2x2(v4), f5 = bf2x2(v5), f6 = bf2x2(v6), f7 = bf2x2(v7);
            a0.x += f0.x; a0.y += f0.y;
            a1.x += f1.x; a1.y += f1.y;
            a2.x += f2.x; a2.y += f2.y;
            a3.x += f3.x; a3.y += f3.y;
            a4.x += f4.x; a4.y += f4.y;
            a5.x += f5.x; a5.y += f5.y;
            a6.x += f6.x; a6.y += f6.y;
            a7.x += f7.x; a7.y += f7.y;
        }
        for (; j < e; ++j) {
            int s = esrc[j];
            float2 v = bf2x2(*(const unsigned int*)&g[(size_t)s * 128 + lane * 2]);
            a0.x += v.x; a0.y += v.y;
        }
        float2 acc = {((a0.x + a1.x) + (a2.x + a3.x)) + ((a4.x + a5.x) + (a6.x + a7.x)),
                      ((a0.y + a1.y) + (a2.y + a3.y)) + ((a4.y + a5.y) + (a6.y + a7.y))};
        const float di = dinv[node];
        float2 hv = {fmaf(acc.x, di, bias.x), fmaf(acc.y, di, bias.y)};
        *(float2*)&h1[(size_t)node * 128 + lane * 2] = hv;
        psum.x += hv.x; psum.y += hv.y;
        psq.x = fmaf(hv.x, hv.x, psq.x);
        psq.y = fmaf(hv.y, hv.y, psq.y);
    }
    sSum[wid][lane] = psum;
    sSq[wid][lane] = psq;
    __syncthreads();
    if (threadIdx.x < 64) {
        float2 a = sSum[0][lane], b = sSum[1][lane], c = sSum[2][lane], d = sSum[3][lane];
        atomicAdd(&stats[lane * 2 + 0], a.x + b.x + c.x + d.x);
        atomicAdd(&stats[lane * 2 + 1], a.y + b.y + c.y + d.y);
        a = sSq[0][lane]; b = sSq[1][lane]; c = sSq[2][lane]; d = sSq[3][lane];
        atomicAdd(&stats[128 + lane * 2 + 0], a.x + b.x + c.x + d.x);
        atomicAdd(&stats[128 + lane * 2 + 1], a.y + b.y + c.y + d.y);
    }
}

// ---------------- BN scale/shift from sums ----------------
__global__ void k_bnfinal(float* __restrict__ stats, const float* __restrict__ gamma,
                          const float* __restrict__ beta, int n) {
    int f = threadIdx.x;  // 128 threads
    float inv_n = 1.f / (float)n;
    float mean = stats[f] * inv_n;
    float var = stats[128 + f] * inv_n - mean * mean;
    float sc = gamma[f] * rsqrtf(var + BN_EPS);
    stats[256 + f] = sc;
    stats[384 + f] = fmaf(-mean, sc, beta[f]);
}

// ---------------- GEMM2: g2 = bf16( dinv ⊙ (relu(BN(h1)) @ W2^T) ) ----------------
__global__ __launch_bounds__(256) void k_gemm2(const float* __restrict__ h1,
                                               const float* __restrict__ W2,
                                               const float* __restrict__ dinv,
                                               const float* __restrict__ stats,
                                               unsigned short* __restrict__ g2, int n) {
    __shared__ float As[16][68];
    __shared__ float Bs[16][68];
    __shared__ float sSc[128], sSh[128];
    const int tid = threadIdx.x;
    if (tid < 128) {
        sSc[tid] = stats[256 + tid];
        sSh[tid] = stats[384 + tid];
    }
    const int row0 = blockIdx.x * 64;
    const int tx = tid & 15, ty = tid >> 4;
    float acc[4][4] = {};
    __syncthreads();
    for (int k0 = 0; k0 < 128; k0 += 16) {
        {
            int r = tid >> 2;
            int kk4 = (tid & 3) * 4;
            int grow = row0 + r;
            float4 v = make_float4(0.f, 0.f, 0.f, 0.f);
            if (grow < n) v = *(const float4*)&h1[(size_t)grow * 128 + k0 + kk4];
            int k = k0 + kk4;
            As[kk4 + 0][r] = fmaxf(fmaf(v.x, sSc[k + 0], sSh[k + 0]), 0.f);
            As[kk4 + 1][r] = fmaxf(fmaf(v.y, sSc[k + 1], sSh[k + 1]), 0.f);
            As[kk4 + 2][r] = fmaxf(fmaf(v.z, sSc[k + 2], sSh[k + 2]), 0.f);
            As[kk4 + 3][r] = fmaxf(fmaf(v.w, sSc[k + 3], sSh[k + 3]), 0.f);
        }
        {
            int j = tid >> 2;
            int kb = (tid & 3) * 4;
            float4 v = *(const float4*)&W2[(size_t)j * 128 + k0 + kb];
            Bs[kb + 0][j] = v.x; Bs[kb + 1][j] = v.y;
            Bs[kb + 2][j] = v.z; Bs[kb + 3][j] = v.w;
        }
        __syncthreads();
#pragma unroll
        for (int kk = 0; kk < 16; ++kk) {
            float4 a = *(const float4*)&As[kk][ty * 4];
            float4 b = *(const float4*)&Bs[kk][tx * 4];
            float aa[4] = {a.x, a.y, a.z, a.w};
            float bb[4] = {b.x, b.y, b.z, b.w};
#pragma unroll
            for (int r = 0; r < 4; ++r)
#pragma unroll
                for (int c = 0; c < 4; ++c) acc[r][c] = fmaf(aa[r], bb[c], acc[r][c]);
        }
        __syncthreads();
    }
#pragma unroll
    for (int r = 0; r < 4; ++r) {
        int grow = row0 + ty * 4 + r;
        if (grow < n) {
            float di = dinv[grow];
            ushort4 u;
            u.x = f2bf(acc[r][0] * di);
            u.y = f2bf(acc[r][1] * di);
            u.z = f2bf(acc[r][2] * di);
            u.w = f2bf(acc[r][3] * di);
            *(ushort4*)&g2[(size_t)grow * 64 + tx * 4] = u;
        }
    }
}

// ---------------- pull2: out[d] = dinv[d]*(g2[d] + sum g2[src]) + b2 ----------------
__global__ __launch_bounds__(256) void k_pull2(const int* __restrict__ rowptr, const int* __restrict__ rowend,
                                               const int* __restrict__ esrc, const unsigned short* __restrict__ g,
                                               const float* __restrict__ dinv, const float* __restrict__ b2,
                                               float* __restrict__ out, int n) {
    const int wid = threadIdx.x >> 6, lane = threadIdx.x & 63;
    const int gw = blockIdx.x * 4 + wid;
    const int nw = gridDim.x * 4;
    const float bias = b2[lane];
    for (int node = gw; node < n; node += nw) {
        const int b = rowptr[node], e = rowend[node];
        float a0 = bf2f(g[(size_t)node * 64 + lane]);  // self loop
        float a1 = 0.f, a2 = 0.f, a3 = 0.f, a4 = 0.f, a5 = 0.f, a6 = 0.f, a7 = 0.f;
        int j = b;
        for (; j + 8 <= e; j += 8) {
            int s0 = esrc[j + 0], s1 = esrc[j + 1], s2 = esrc[j + 2], s3 = esrc[j + 3];
            int s4 = esrc[j + 4], s5 = esrc[j + 5], s6 = esrc[j + 6], s7 = esrc[j + 7];
            unsigned short v0 = g[(size_t)s0 * 64 + lane];
            unsigned short v1 = g[(size_t)s1 * 64 + lane];
            unsigned short v2 = g[(size_t)s2 * 64 + lane];
            unsigned short v3 = g[(size_t)s3 * 64 + lane];
            unsigned short v4 = g[(size_t)s4 * 64 + lane];
            unsigned short v5 = g[(size_t)s5 * 64 + lane];
            unsigned short v6 = g[(size_t)s6 * 64 + lane];
            unsigned short v7 = g[(size_t)s7 * 64 + lane];
            a0 += bf2f(v0); a1 += bf2f(v1); a2 += bf2f(v2); a3 += bf2f(v3);
            a4 += bf2f(v4); a5 += bf2f(v5); a6 += bf2f(v6); a7 += bf2f(v7);
        }
        for (; j < e; ++j) a0 += bf2f(g[(size_t)esrc[j] * 64 + lane]);
        float acc = ((a0 + a1) + (a2 + a3)) + ((a4 + a5) + (a6 + a7));
        out[(size_t)node * 64 + lane] = fmaf(acc, dinv[node], bias);
    }
}

extern "C" void kernel_launch(void* const* d_in, const int* in_sizes, int n_in,
                              void* d_out, int out_size, void* d_ws, size_t ws_size,
                              hipStream_t stream) {
    const float* x     = (const float*)d_in[0];
    const int*   ei    = (const int*)d_in[1];
    const float* W1    = (const float*)d_in[2];
    const float* b1    = (const float*)d_in[3];
    const float* gamma = (const float*)d_in[4];
    const float* beta  = (const float*)d_in[5];
    const float* W2    = (const float*)d_in[6];
    const float* b2    = (const float*)d_in[7];
    float* out = (float*)d_out;

    const int n = in_sizes[0] / 128;
    const int E = in_sizes[1] / 2;
    const int* src = ei;
    const int* dst = ei + E;

    char* ws = (char*)d_ws;
    const int Np = (n + 255) & ~255;
    const int Ep = (E + 3) & ~3;
    int*   deg    = (int*)ws;
    int*   rowptr = deg + Np;
    int*   cursor = rowptr + Np;
    float* dinv   = (float*)(cursor + Np);
    float* stats  = dinv + Np;
    int*   bsum   = (int*)(stats + 512);
    int*   bofs   = bsum + 1024;
    int*   esrc   = bofs + 1024;
    unsigned short* g1 = (unsigned short*)(esrc + Ep);     // n*128 bf16
    float* h1     = (float*)(g1 + (size_t)n * 128);        // n*128 f32
    unsigned short* g2 = g1;                               // reuse (g1 dead after pull1)

    const int nb = (n + 255) / 256;
    const int nscan = (n + 1023) / 1024;
    const int gb = (n + 63) / 64;

    hipLaunchKernelGGL(k_init, dim3(nb), dim3(256), 0, stream, deg, stats, n);
    hipLaunchKernelGGL(k_count, dim3(1024), dim3(256), 0, stream, dst, deg, E);
    hipLaunchKernelGGL(k_blocksum, dim3(nscan), dim3(256), 0, stream, deg, bsum, n);
    hipLaunchKernelGGL(k_scanbsums, dim3(1), dim3(256), 0, stream, bsum, bofs, nscan);
    hipLaunchKernelGGL(k_scan_apply, dim3(nscan), dim3(256), 0, stream, deg, bofs, rowptr, cursor, dinv, n);

    hipLaunchKernelGGL(k_gemm1, dim3(gb), dim3(256), 0, stream, x, W1, dinv, g1, n);
    hipLaunchKernelGGL(k_permute, dim3(1024), dim3(256), 0, stream, src, dst, cursor, esrc, E);
    hipLaunchKernelGGL(k_pull1, dim3(2048), dim3(256), 0, stream, rowptr, cursor, esrc, g1, dinv, b1, h1, stats, n);
    hipLaunchKernelGGL(k_bnfinal, dim3(1), dim3(128), 0, stream, stats, gamma, beta, n);

    hipLaunchKernelGGL(k_gemm2, dim3(gb), dim3(256), 0, stream, h1, W2, dinv, stats, g2, n);
    hipLaunchKernelGGL(k_pull2, dim3(2048), dim3(256), 0, stream, rowptr, cursor, esrc, g2, dinv, b2, out, n);
}